// Round 3
// baseline (2197.653 us; speedup 1.0000x reference)
//
#include <hip/hip_runtime.h>
#include <math.h>

#define NROWS (512 * 512)   // B*T = 262144
#define KCB   1024          // codebook size
#define DDIM  64            // embedding dim
#define TK    128           // k-tile staged in LDS (128*64*4B = 32 KB)
#define RPT   4             // rows per thread
#define NQ    ((size_t)NROWS * DDIM)

// B_k = sum_i weight[k][i]^2, fp32, numpy pairwise-8 pattern
__global__ void wsq_kernel(const float* __restrict__ w, float* __restrict__ bsq) {
    int k = blockIdx.x * blockDim.x + threadIdx.x;
    if (k >= KCB) return;
    const float* row = w + (size_t)k * DDIM;
    float r[8];
#pragma unroll
    for (int j = 0; j < 8; ++j) r[j] = __fmul_rn(row[j], row[j]);
#pragma unroll
    for (int i = 8; i < DDIM; i += 8)
#pragma unroll
        for (int j = 0; j < 8; ++j)
            r[j] = __fadd_rn(r[j], __fmul_rn(row[i + j], row[i + j]));
    bsq[k] = __fadd_rn(__fadd_rn(__fadd_rn(r[0], r[1]), __fadd_rn(r[2], r[3])),
                       __fadd_rn(__fadd_rn(r[4], r[5]), __fadd_rn(r[6], r[7])));
}

__global__ __launch_bounds__(256, 1)
void vq_main(const float* __restrict__ h, const float* __restrict__ w,
             const float* __restrict__ bsq, float* __restrict__ out) {
    __shared__ float wl[TK * DDIM];   // 32 KB weight tile
    __shared__ float bl[TK];

    const int tid = threadIdx.x;
    const size_t rowbase = (size_t)blockIdx.x * (256 * RPT) + (size_t)tid * RPT;

    // 4 h rows -> 256 VGPRs
    float hr[RPT][DDIM];
#pragma unroll
    for (int r = 0; r < RPT; ++r) {
        const float* hrow = h + (rowbase + r) * DDIM;
#pragma unroll
        for (int i = 0; i < DDIM; i += 4) {
            float4 v = *reinterpret_cast<const float4*>(hrow + i);
            hr[r][i] = v.x; hr[r][i + 1] = v.y; hr[r][i + 2] = v.z; hr[r][i + 3] = v.w;
        }
    }

    // A_r = (h**2).sum per row, numpy pairwise-8 ordering
    float A[RPT];
#pragma unroll
    for (int r = 0; r < RPT; ++r) {
        float s[8];
#pragma unroll
        for (int j = 0; j < 8; ++j) s[j] = __fmul_rn(hr[r][j], hr[r][j]);
#pragma unroll
        for (int i = 8; i < DDIM; i += 8)
#pragma unroll
            for (int j = 0; j < 8; ++j)
                s[j] = __fadd_rn(s[j], __fmul_rn(hr[r][i + j], hr[r][i + j]));
        A[r] = __fadd_rn(__fadd_rn(__fadd_rn(s[0], s[1]), __fadd_rn(s[2], s[3])),
                         __fadd_rn(__fadd_rn(s[4], s[5]), __fadd_rn(s[6], s[7])));
    }

    float best[RPT];
    int bestk[RPT];
#pragma unroll
    for (int r = 0; r < RPT; ++r) { best[r] = INFINITY; bestk[r] = 0; }

#pragma unroll 1
    for (int t0 = 0; t0 < KCB; t0 += TK) {
        __syncthreads();
        const float4* wsrc = reinterpret_cast<const float4*>(w + (size_t)t0 * DDIM);
        float4* wdst = reinterpret_cast<float4*>(wl);
#pragma unroll
        for (int j = 0; j < 8; ++j) wdst[j * 256 + tid] = wsrc[j * 256 + tid];
        if (tid < TK) bl[tid] = bsq[t0 + tid];
        __syncthreads();

#pragma unroll 2
        for (int kq = 0; kq < TK; kq += 2) {
            const float* w0p = wl + (kq + 0) * DDIM;
            const float* w1p = wl + (kq + 1) * DDIM;
            float a[RPT][2];
#pragma unroll
            for (int r = 0; r < RPT; ++r) { a[r][0] = 0.f; a[r][1] = 0.f; }
#pragma unroll
            for (int i = 0; i < DDIM; i += 4) {
                float4 x0 = *reinterpret_cast<const float4*>(w0p + i);
                float4 x1 = *reinterpret_cast<const float4*>(w1p + i);
#pragma unroll
                for (int r = 0; r < RPT; ++r) {
                    // k-ascending single-accumulator chains, ascending d (frozen order)
                    a[r][0] = fmaf(hr[r][i + 0], x0.x, a[r][0]);
                    a[r][0] = fmaf(hr[r][i + 1], x0.y, a[r][0]);
                    a[r][0] = fmaf(hr[r][i + 2], x0.z, a[r][0]);
                    a[r][0] = fmaf(hr[r][i + 3], x0.w, a[r][0]);
                    a[r][1] = fmaf(hr[r][i + 0], x1.x, a[r][1]);
                    a[r][1] = fmaf(hr[r][i + 1], x1.y, a[r][1]);
                    a[r][1] = fmaf(hr[r][i + 2], x1.z, a[r][1]);
                    a[r][1] = fmaf(hr[r][i + 3], x1.w, a[r][1]);
                }
            }
            float b0 = bl[kq + 0], b1 = bl[kq + 1];
#pragma unroll
            for (int r = 0; r < RPT; ++r) {
                float d0 = __fsub_rn(__fadd_rn(A[r], b0), __fadd_rn(a[r][0], a[r][0]));
                float d1 = __fsub_rn(__fadd_rn(A[r], b1), __fadd_rn(a[r][1], a[r][1]));
                if (d0 < best[r]) { best[r] = d0; bestk[r] = t0 + kq + 0; }
                if (d1 < best[r]) { best[r] = d1; bestk[r] = t0 + kq + 1; }
            }
        }
    }

    // ---- epilogue (all f32): qst = h + (q - h); loss; idx ----
#pragma unroll
    for (int r = 0; r < RPT; ++r) {
        const size_t n = rowbase + r;
        const float* qrow = w + (size_t)bestk[r] * DDIM;
        float* qst = out + n * DDIM;
        float r2[8];
#pragma unroll
        for (int c = 0; c < 8; ++c) {
            float4 qa = *reinterpret_cast<const float4*>(qrow + 8 * c);
            float4 qb = *reinterpret_cast<const float4*>(qrow + 8 * c + 4);
            float d0 = __fsub_rn(qa.x, hr[r][8 * c + 0]);
            float d1 = __fsub_rn(qa.y, hr[r][8 * c + 1]);
            float d2 = __fsub_rn(qa.z, hr[r][8 * c + 2]);
            float d3 = __fsub_rn(qa.w, hr[r][8 * c + 3]);
            float d4 = __fsub_rn(qb.x, hr[r][8 * c + 4]);
            float d5 = __fsub_rn(qb.y, hr[r][8 * c + 5]);
            float d6 = __fsub_rn(qb.z, hr[r][8 * c + 6]);
            float d7 = __fsub_rn(qb.w, hr[r][8 * c + 7]);
            if (c == 0) {
                r2[0] = __fmul_rn(d0, d0); r2[1] = __fmul_rn(d1, d1);
                r2[2] = __fmul_rn(d2, d2); r2[3] = __fmul_rn(d3, d3);
                r2[4] = __fmul_rn(d4, d4); r2[5] = __fmul_rn(d5, d5);
                r2[6] = __fmul_rn(d6, d6); r2[7] = __fmul_rn(d7, d7);
            } else {
                r2[0] = __fadd_rn(r2[0], __fmul_rn(d0, d0));
                r2[1] = __fadd_rn(r2[1], __fmul_rn(d1, d1));
                r2[2] = __fadd_rn(r2[2], __fmul_rn(d2, d2));
                r2[3] = __fadd_rn(r2[3], __fmul_rn(d3, d3));
                r2[4] = __fadd_rn(r2[4], __fmul_rn(d4, d4));
                r2[5] = __fadd_rn(r2[5], __fmul_rn(d5, d5));
                r2[6] = __fadd_rn(r2[6], __fmul_rn(d6, d6));
                r2[7] = __fadd_rn(r2[7], __fmul_rn(d7, d7));
            }
            float4 oa, ob;
            oa.x = __fadd_rn(hr[r][8 * c + 0], d0);
            oa.y = __fadd_rn(hr[r][8 * c + 1], d1);
            oa.z = __fadd_rn(hr[r][8 * c + 2], d2);
            oa.w = __fadd_rn(hr[r][8 * c + 3], d3);
            ob.x = __fadd_rn(hr[r][8 * c + 4], d4);
            ob.y = __fadd_rn(hr[r][8 * c + 5], d5);
            ob.z = __fadd_rn(hr[r][8 * c + 6], d6);
            ob.w = __fadd_rn(hr[r][8 * c + 7], d7);
            *reinterpret_cast<float4*>(qst + 8 * c) = oa;
            *reinterpret_cast<float4*>(qst + 8 * c + 4) = ob;
        }
        float S = __fadd_rn(__fadd_rn(__fadd_rn(r2[0], r2[1]), __fadd_rn(r2[2], r2[3])),
                            __fadd_rn(__fadd_rn(r2[4], r2[5]), __fadd_rn(r2[6], r2[7])));
        float m = __fmul_rn(S, 0.015625f);
        float loss = __fadd_rn(__fmul_rn(m, 0.1f), __fmul_rn(m, 0.2f));
        out[NQ + n] = (float)bestk[r];
        out[NQ + NROWS + n] = loss;
    }
}

extern "C" void kernel_launch(void* const* d_in, const int* in_sizes, int n_in,
                              void* d_out, int out_size, void* d_ws, size_t ws_size,
                              hipStream_t stream) {
    (void)in_sizes; (void)n_in; (void)out_size; (void)ws_size;
    const float* h = (const float*)d_in[0];
    const float* w = (const float*)d_in[1];
    float* bsq = (float*)d_ws;
    float* out = (float*)d_out;

    wsq_kernel<<<(KCB + 255) / 256, 256, 0, stream>>>(w, bsq);
    vq_main<<<NROWS / (256 * RPT), 256, 0, stream>>>(h, w, bsq, out);
}

// Round 4
// 751.291 us; speedup vs baseline: 2.9252x; 2.9252x over previous
//
#include <hip/hip_runtime.h>
#include <math.h>

#define NROWS (512 * 512)   // B*T = 262144
#define KCB   1024          // codebook size
#define DDIM  64            // embedding dim
#define RPT   2             // rows per thread (hr = 128 VGPR; RPT=4 spills — R3)
#define NQ    ((size_t)NROWS * DDIM)

// B_k = sum_i weight[k][i]^2, fp32, numpy pairwise-8 pattern
__global__ void wsq_kernel(const float* __restrict__ w, float* __restrict__ bsq) {
    int k = blockIdx.x * blockDim.x + threadIdx.x;
    if (k >= KCB) return;
    const float* row = w + (size_t)k * DDIM;
    float r[8];
#pragma unroll
    for (int j = 0; j < 8; ++j) r[j] = __fmul_rn(row[j], row[j]);
#pragma unroll
    for (int i = 8; i < DDIM; i += 8)
#pragma unroll
        for (int j = 0; j < 8; ++j)
            r[j] = __fadd_rn(r[j], __fmul_rn(row[i + j], row[i + j]));
    bsq[k] = __fadd_rn(__fadd_rn(__fadd_rn(r[0], r[1]), __fadd_rn(r[2], r[3])),
                       __fadd_rn(__fadd_rn(r[4], r[5]), __fadd_rn(r[6], r[7])));
}

// w consumed via wave-uniform addresses -> scalar loads (s_load) + SGPR-operand FMAs.
// No LDS at all: w traffic rides the scalar/SMEM pipe, FMA chain owns the VALU.
__global__ __launch_bounds__(256, 2)
void vq_main(const float* __restrict__ h, const float* __restrict__ w,
             const float* __restrict__ bsq, float* __restrict__ out) {
    const int tid = threadIdx.x;
    const size_t rowbase = (size_t)blockIdx.x * (256 * RPT) + (size_t)tid * RPT;

    // 2 h rows -> 128 VGPRs
    float hr[RPT][DDIM];
#pragma unroll
    for (int r = 0; r < RPT; ++r) {
        const float* hrow = h + (rowbase + r) * DDIM;
#pragma unroll
        for (int i = 0; i < DDIM; i += 4) {
            float4 v = *reinterpret_cast<const float4*>(hrow + i);
            hr[r][i] = v.x; hr[r][i + 1] = v.y; hr[r][i + 2] = v.z; hr[r][i + 3] = v.w;
        }
    }

    // A_r = (h**2).sum per row, numpy pairwise-8 ordering (frozen — validated R2)
    float A[RPT];
#pragma unroll
    for (int r = 0; r < RPT; ++r) {
        float s[8];
#pragma unroll
        for (int j = 0; j < 8; ++j) s[j] = __fmul_rn(hr[r][j], hr[r][j]);
#pragma unroll
        for (int i = 8; i < DDIM; i += 8)
#pragma unroll
            for (int j = 0; j < 8; ++j)
                s[j] = __fadd_rn(s[j], __fmul_rn(hr[r][i + j], hr[r][i + j]));
        A[r] = __fadd_rn(__fadd_rn(__fadd_rn(s[0], s[1]), __fadd_rn(s[2], s[3])),
                         __fadd_rn(__fadd_rn(s[4], s[5]), __fadd_rn(s[6], s[7])));
    }

    float best[RPT];
    int bestk[RPT];
#pragma unroll
    for (int r = 0; r < RPT; ++r) { best[r] = INFINITY; bestk[r] = 0; }

#pragma unroll 1
    for (int k0 = 0; k0 < KCB; k0 += 2) {
        const float* w0p = w + (size_t)k0 * DDIM;        // wave-uniform address
        const float* w1p = w0p + DDIM;
        float a[RPT][2];
#pragma unroll
        for (int r = 0; r < RPT; ++r) { a[r][0] = 0.f; a[r][1] = 0.f; }
#pragma unroll
        for (int i = 0; i < DDIM; i += 4) {
            float4 x0 = *reinterpret_cast<const float4*>(w0p + i);  // -> s_load
            float4 x1 = *reinterpret_cast<const float4*>(w1p + i);  // -> s_load
#pragma unroll
            for (int r = 0; r < RPT; ++r) {
                // k-ascending single-accumulator chains, ascending d (frozen order)
                a[r][0] = fmaf(hr[r][i + 0], x0.x, a[r][0]);
                a[r][0] = fmaf(hr[r][i + 1], x0.y, a[r][0]);
                a[r][0] = fmaf(hr[r][i + 2], x0.z, a[r][0]);
                a[r][0] = fmaf(hr[r][i + 3], x0.w, a[r][0]);
                a[r][1] = fmaf(hr[r][i + 0], x1.x, a[r][1]);
                a[r][1] = fmaf(hr[r][i + 1], x1.y, a[r][1]);
                a[r][1] = fmaf(hr[r][i + 2], x1.z, a[r][1]);
                a[r][1] = fmaf(hr[r][i + 3], x1.w, a[r][1]);
            }
        }
        float b0 = bsq[k0], b1 = bsq[k0 + 1];            // wave-uniform -> s_load
#pragma unroll
        for (int r = 0; r < RPT; ++r) {
            float d0 = __fsub_rn(__fadd_rn(A[r], b0), __fadd_rn(a[r][0], a[r][0]));
            float d1 = __fsub_rn(__fadd_rn(A[r], b1), __fadd_rn(a[r][1], a[r][1]));
            if (d0 < best[r]) { best[r] = d0; bestk[r] = k0 + 0; }
            if (d1 < best[r]) { best[r] = d1; bestk[r] = k0 + 1; }
        }
    }

    // ---- epilogue (all f32): qst = h + (q - h); loss; idx ---- (frozen — validated R2)
#pragma unroll
    for (int r = 0; r < RPT; ++r) {
        const size_t n = rowbase + r;
        const float* qrow = w + (size_t)bestk[r] * DDIM;
        float* qst = out + n * DDIM;
        float r2[8];
#pragma unroll
        for (int c = 0; c < 8; ++c) {
            float4 qa = *reinterpret_cast<const float4*>(qrow + 8 * c);
            float4 qb = *reinterpret_cast<const float4*>(qrow + 8 * c + 4);
            float d0 = __fsub_rn(qa.x, hr[r][8 * c + 0]);
            float d1 = __fsub_rn(qa.y, hr[r][8 * c + 1]);
            float d2 = __fsub_rn(qa.z, hr[r][8 * c + 2]);
            float d3 = __fsub_rn(qa.w, hr[r][8 * c + 3]);
            float d4 = __fsub_rn(qb.x, hr[r][8 * c + 4]);
            float d5 = __fsub_rn(qb.y, hr[r][8 * c + 5]);
            float d6 = __fsub_rn(qb.z, hr[r][8 * c + 6]);
            float d7 = __fsub_rn(qb.w, hr[r][8 * c + 7]);
            if (c == 0) {
                r2[0] = __fmul_rn(d0, d0); r2[1] = __fmul_rn(d1, d1);
                r2[2] = __fmul_rn(d2, d2); r2[3] = __fmul_rn(d3, d3);
                r2[4] = __fmul_rn(d4, d4); r2[5] = __fmul_rn(d5, d5);
                r2[6] = __fmul_rn(d6, d6); r2[7] = __fmul_rn(d7, d7);
            } else {
                r2[0] = __fadd_rn(r2[0], __fmul_rn(d0, d0));
                r2[1] = __fadd_rn(r2[1], __fmul_rn(d1, d1));
                r2[2] = __fadd_rn(r2[2], __fmul_rn(d2, d2));
                r2[3] = __fadd_rn(r2[3], __fmul_rn(d3, d3));
                r2[4] = __fadd_rn(r2[4], __fmul_rn(d4, d4));
                r2[5] = __fadd_rn(r2[5], __fmul_rn(d5, d5));
                r2[6] = __fadd_rn(r2[6], __fmul_rn(d6, d6));
                r2[7] = __fadd_rn(r2[7], __fmul_rn(d7, d7));
            }
            float4 oa, ob;
            oa.x = __fadd_rn(hr[r][8 * c + 0], d0);
            oa.y = __fadd_rn(hr[r][8 * c + 1], d1);
            oa.z = __fadd_rn(hr[r][8 * c + 2], d2);
            oa.w = __fadd_rn(hr[r][8 * c + 3], d3);
            ob.x = __fadd_rn(hr[r][8 * c + 4], d4);
            ob.y = __fadd_rn(hr[r][8 * c + 5], d5);
            ob.z = __fadd_rn(hr[r][8 * c + 6], d6);
            ob.w = __fadd_rn(hr[r][8 * c + 7], d7);
            *reinterpret_cast<float4*>(qst + 8 * c) = oa;
            *reinterpret_cast<float4*>(qst + 8 * c + 4) = ob;
        }
        float S = __fadd_rn(__fadd_rn(__fadd_rn(r2[0], r2[1]), __fadd_rn(r2[2], r2[3])),
                            __fadd_rn(__fadd_rn(r2[4], r2[5]), __fadd_rn(r2[6], r2[7])));
        float m = __fmul_rn(S, 0.015625f);
        float loss = __fadd_rn(__fmul_rn(m, 0.1f), __fmul_rn(m, 0.2f));
        out[NQ + n] = (float)bestk[r];
        out[NQ + NROWS + n] = loss;
    }
}

extern "C" void kernel_launch(void* const* d_in, const int* in_sizes, int n_in,
                              void* d_out, int out_size, void* d_ws, size_t ws_size,
                              hipStream_t stream) {
    (void)in_sizes; (void)n_in; (void)out_size; (void)ws_size;
    const float* h = (const float*)d_in[0];
    const float* w = (const float*)d_in[1];
    float* bsq = (float*)d_ws;
    float* out = (float*)d_out;

    wsq_kernel<<<(KCB + 255) / 256, 256, 0, stream>>>(w, bsq);
    vq_main<<<NROWS / (256 * RPT), 256, 0, stream>>>(h, w, bsq, out);
}

// Round 5
// 495.472 us; speedup vs baseline: 4.4355x; 1.5163x over previous
//
#include <hip/hip_runtime.h>
#include <math.h>

#define NROWS (512 * 512)   // B*T = 262144
#define KCB   1024          // codebook size
#define DDIM  64            // embedding dim
#define TK    128           // k-tile staged in LDS (32 KB)
#define RPT   2             // rows per thread (hr=128 VGPR; RPT=4 spills — R3)
#define NQ    ((size_t)NROWS * DDIM)

// B_k = sum_i weight[k][i]^2, fp32, numpy pairwise-8 pattern
__global__ void wsq_kernel(const float* __restrict__ w, float* __restrict__ bsq) {
    int k = blockIdx.x * blockDim.x + threadIdx.x;
    if (k >= KCB) return;
    const float* row = w + (size_t)k * DDIM;
    float r[8];
#pragma unroll
    for (int j = 0; j < 8; ++j) r[j] = __fmul_rn(row[j], row[j]);
#pragma unroll
    for (int i = 8; i < DDIM; i += 8)
#pragma unroll
        for (int j = 0; j < 8; ++j)
            r[j] = __fadd_rn(r[j], __fmul_rn(row[i + j], row[i + j]));
    bsq[k] = __fadd_rn(__fadd_rn(__fadd_rn(r[0], r[1]), __fadd_rn(r[2], r[3])),
                       __fadd_rn(__fadd_rn(r[4], r[5]), __fadd_rn(r[6], r[7])));
}

// R2's LDS-broadcast feed + RPT=2: each uniform ds_read_b128 now feeds 8 FMAs.
__global__ __launch_bounds__(256, 2)
void vq_main(const float* __restrict__ h, const float* __restrict__ w,
             const float* __restrict__ bsq, float* __restrict__ out) {
    __shared__ float wl[TK * DDIM];   // 32 KB weight tile
    __shared__ float bl[TK];

    const int tid = threadIdx.x;
    const size_t rowbase = (size_t)blockIdx.x * (256 * RPT) + (size_t)tid * RPT;

    // 2 h rows -> 128 VGPRs
    float hr[RPT][DDIM];
#pragma unroll
    for (int r = 0; r < RPT; ++r) {
        const float* hrow = h + (rowbase + r) * DDIM;
#pragma unroll
        for (int i = 0; i < DDIM; i += 4) {
            float4 v = *reinterpret_cast<const float4*>(hrow + i);
            hr[r][i] = v.x; hr[r][i + 1] = v.y; hr[r][i + 2] = v.z; hr[r][i + 3] = v.w;
        }
    }

    // A_r = (h**2).sum per row, numpy pairwise-8 ordering (frozen — validated R2)
    float A[RPT];
#pragma unroll
    for (int r = 0; r < RPT; ++r) {
        float s[8];
#pragma unroll
        for (int j = 0; j < 8; ++j) s[j] = __fmul_rn(hr[r][j], hr[r][j]);
#pragma unroll
        for (int i = 8; i < DDIM; i += 8)
#pragma unroll
            for (int j = 0; j < 8; ++j)
                s[j] = __fadd_rn(s[j], __fmul_rn(hr[r][i + j], hr[r][i + j]));
        A[r] = __fadd_rn(__fadd_rn(__fadd_rn(s[0], s[1]), __fadd_rn(s[2], s[3])),
                         __fadd_rn(__fadd_rn(s[4], s[5]), __fadd_rn(s[6], s[7])));
    }

    float best[RPT];
    int bestk[RPT];
#pragma unroll
    for (int r = 0; r < RPT; ++r) { best[r] = INFINITY; bestk[r] = 0; }

#pragma unroll 1
    for (int t0 = 0; t0 < KCB; t0 += TK) {
        __syncthreads();
        // cooperative stage: 2048 float4s across 256 threads, coalesced
        const float4* wsrc = reinterpret_cast<const float4*>(w + (size_t)t0 * DDIM);
        float4* wdst = reinterpret_cast<float4*>(wl);
#pragma unroll
        for (int j = 0; j < 8; ++j) wdst[j * 256 + tid] = wsrc[j * 256 + tid];
        if (tid < TK) bl[tid] = bsq[t0 + tid];
        __syncthreads();

#pragma unroll 2
        for (int kq = 0; kq < TK; kq += 2) {
            const float* w0p = wl + (kq + 0) * DDIM;   // wave-uniform LDS address
            const float* w1p = wl + (kq + 1) * DDIM;
            float a[RPT][2];
#pragma unroll
            for (int r = 0; r < RPT; ++r) { a[r][0] = 0.f; a[r][1] = 0.f; }
#pragma unroll
            for (int i = 0; i < DDIM; i += 4) {
                float4 x0 = *reinterpret_cast<const float4*>(w0p + i);  // uniform b128 broadcast
                float4 x1 = *reinterpret_cast<const float4*>(w1p + i);
#pragma unroll
                for (int r = 0; r < RPT; ++r) {
                    // k-ascending single-accumulator chains, ascending d (frozen order)
                    a[r][0] = fmaf(hr[r][i + 0], x0.x, a[r][0]);
                    a[r][0] = fmaf(hr[r][i + 1], x0.y, a[r][0]);
                    a[r][0] = fmaf(hr[r][i + 2], x0.z, a[r][0]);
                    a[r][0] = fmaf(hr[r][i + 3], x0.w, a[r][0]);
                    a[r][1] = fmaf(hr[r][i + 0], x1.x, a[r][1]);
                    a[r][1] = fmaf(hr[r][i + 1], x1.y, a[r][1]);
                    a[r][1] = fmaf(hr[r][i + 2], x1.z, a[r][1]);
                    a[r][1] = fmaf(hr[r][i + 3], x1.w, a[r][1]);
                }
            }
            float b0 = bl[kq + 0], b1 = bl[kq + 1];
#pragma unroll
            for (int r = 0; r < RPT; ++r) {
                float d0 = __fsub_rn(__fadd_rn(A[r], b0), __fadd_rn(a[r][0], a[r][0]));
                float d1 = __fsub_rn(__fadd_rn(A[r], b1), __fadd_rn(a[r][1], a[r][1]));
                if (d0 < best[r]) { best[r] = d0; bestk[r] = t0 + kq + 0; }
                if (d1 < best[r]) { best[r] = d1; bestk[r] = t0 + kq + 1; }
            }
        }
    }

    // ---- epilogue (all f32): qst = h + (q - h); loss; idx ---- (frozen — validated R2)
#pragma unroll
    for (int r = 0; r < RPT; ++r) {
        const size_t n = rowbase + r;
        const float* qrow = w + (size_t)bestk[r] * DDIM;
        float* qst = out + n * DDIM;
        float r2[8];
#pragma unroll
        for (int c = 0; c < 8; ++c) {
            float4 qa = *reinterpret_cast<const float4*>(qrow + 8 * c);
            float4 qb = *reinterpret_cast<const float4*>(qrow + 8 * c + 4);
            float d0 = __fsub_rn(qa.x, hr[r][8 * c + 0]);
            float d1 = __fsub_rn(qa.y, hr[r][8 * c + 1]);
            float d2 = __fsub_rn(qa.z, hr[r][8 * c + 2]);
            float d3 = __fsub_rn(qa.w, hr[r][8 * c + 3]);
            float d4 = __fsub_rn(qb.x, hr[r][8 * c + 4]);
            float d5 = __fsub_rn(qb.y, hr[r][8 * c + 5]);
            float d6 = __fsub_rn(qb.z, hr[r][8 * c + 6]);
            float d7 = __fsub_rn(qb.w, hr[r][8 * c + 7]);
            if (c == 0) {
                r2[0] = __fmul_rn(d0, d0); r2[1] = __fmul_rn(d1, d1);
                r2[2] = __fmul_rn(d2, d2); r2[3] = __fmul_rn(d3, d3);
                r2[4] = __fmul_rn(d4, d4); r2[5] = __fmul_rn(d5, d5);
                r2[6] = __fmul_rn(d6, d6); r2[7] = __fmul_rn(d7, d7);
            } else {
                r2[0] = __fadd_rn(r2[0], __fmul_rn(d0, d0));
                r2[1] = __fadd_rn(r2[1], __fmul_rn(d1, d1));
                r2[2] = __fadd_rn(r2[2], __fmul_rn(d2, d2));
                r2[3] = __fadd_rn(r2[3], __fmul_rn(d3, d3));
                r2[4] = __fadd_rn(r2[4], __fmul_rn(d4, d4));
                r2[5] = __fadd_rn(r2[5], __fmul_rn(d5, d5));
                r2[6] = __fadd_rn(r2[6], __fmul_rn(d6, d6));
                r2[7] = __fadd_rn(r2[7], __fmul_rn(d7, d7));
            }
            float4 oa, ob;
            oa.x = __fadd_rn(hr[r][8 * c + 0], d0);
            oa.y = __fadd_rn(hr[r][8 * c + 1], d1);
            oa.z = __fadd_rn(hr[r][8 * c + 2], d2);
            oa.w = __fadd_rn(hr[r][8 * c + 3], d3);
            ob.x = __fadd_rn(hr[r][8 * c + 4], d4);
            ob.y = __fadd_rn(hr[r][8 * c + 5], d5);
            ob.z = __fadd_rn(hr[r][8 * c + 6], d6);
            ob.w = __fadd_rn(hr[r][8 * c + 7], d7);
            *reinterpret_cast<float4*>(qst + 8 * c) = oa;
            *reinterpret_cast<float4*>(qst + 8 * c + 4) = ob;
        }
        float S = __fadd_rn(__fadd_rn(__fadd_rn(r2[0], r2[1]), __fadd_rn(r2[2], r2[3])),
                            __fadd_rn(__fadd_rn(r2[4], r2[5]), __fadd_rn(r2[6], r2[7])));
        float m = __fmul_rn(S, 0.015625f);
        float loss = __fadd_rn(__fmul_rn(m, 0.1f), __fmul_rn(m, 0.2f));
        out[NQ + n] = (float)bestk[r];
        out[NQ + NROWS + n] = loss;
    }
}

extern "C" void kernel_launch(void* const* d_in, const int* in_sizes, int n_in,
                              void* d_out, int out_size, void* d_ws, size_t ws_size,
                              hipStream_t stream) {
    (void)in_sizes; (void)n_in; (void)out_size; (void)ws_size;
    const float* h = (const float*)d_in[0];
    const float* w = (const float*)d_in[1];
    float* bsq = (float*)d_ws;
    float* out = (float*)d_out;

    wsq_kernel<<<(KCB + 255) / 256, 256, 0, stream>>>(w, bsq);
    vq_main<<<NROWS / (256 * RPT), 256, 0, stream>>>(h, w, bsq, out);
}